// Round 1
// 473.609 us; speedup vs baseline: 1.4738x; 1.4738x over previous
//
#include <hip/hip_runtime.h>
#include <hip/hip_bf16.h>
#include <math.h>

// ---------------------------------------------------------------------------
// Qwen3 attention block: T=4096, HIDDEN=2048, 16 Q heads, 8 KV heads,
// HEAD_DIM=128, rope theta 1e6, rms eps 1e-6, causal.
// fp32 in/out; bf16 internally for MFMA with fp32 accumulation.
//
// ws layout (84 MB, regions reused across phases):
//   qkv  bf16 [4096][4096]  @ 0
//   qn   bf16 [4096][2048]  (also wo after attn)
//   kn   bf16 [4096][1024]  (kn+vt region doubles as wq pre-gemm1)
//   vt   bf16 [1024][4096]
//   ao   bf16 [4096][2048]  (doubles as hb pre-attn)
// ---------------------------------------------------------------------------

typedef __bf16 bf16;
typedef __bf16 bf16x4 __attribute__((ext_vector_type(4)));
typedef __bf16 bf16x8 __attribute__((ext_vector_type(8)));
typedef float  f32x4  __attribute__((ext_vector_type(4)));

__device__ __forceinline__ f32x4 mfma16(bf16x8 a, bf16x8 b, f32x4 c) {
  return __builtin_amdgcn_mfma_f32_16x16x32_bf16(a, b, c, 0, 0, 0);
}

// 4 chained 16x16x16 bf16 MFMAs accumulating into one C/D quad.
// A/B frag [m|n = l16][k = quad*4 + j] == S^T C-layout, so P feeds PV directly
// from registers. Single leading s_nop 2 covers the VALU-write -> MFMA-read
// hazard (same-acc MFMA->MFMA chains are HW-interlocked).
__device__ __forceinline__ void mfma16x16_chain4(const bf16x4& a0, const bf16x4& a1,
                                                 const bf16x4& a2, const bf16x4& a3,
                                                 const bf16x4& b0, const bf16x4& b1,
                                                 const bf16x4& b2, const bf16x4& b3,
                                                 f32x4& c) {
  asm volatile(
      "s_nop 2\n\t"
      "v_mfma_f32_16x16x16_bf16 %0, %1, %5, %0\n\t"
      "v_mfma_f32_16x16x16_bf16 %0, %2, %6, %0\n\t"
      "v_mfma_f32_16x16x16_bf16 %0, %3, %7, %0\n\t"
      "v_mfma_f32_16x16x16_bf16 %0, %4, %8, %0"
      : "+v"(c)
      : "v"(a0), "v"(a1), "v"(a2), "v"(a3),
        "v"(b0), "v"(b1), "v"(b2), "v"(b3));
}

// Async global->LDS DMA, 16B per lane. LDS dest is wave-uniform base +
// lane*16 (hardware rule); global src is per-lane.
__device__ __forceinline__ void gload_lds16(const bf16* g, bf16* l) {
  __builtin_amdgcn_global_load_lds(
      (const __attribute__((address_space(1))) unsigned int*)g,
      (__attribute__((address_space(3))) unsigned int*)l, 16, 0, 0);
}

__device__ __forceinline__ void load8_to_lds(const float* src, bf16* dst) {
  float4 a = *reinterpret_cast<const float4*>(src);
  float4 b = *reinterpret_cast<const float4*>(src + 4);
  bf16x8 v = {(bf16)a.x, (bf16)a.y, (bf16)a.z, (bf16)a.w,
              (bf16)b.x, (bf16)b.y, (bf16)b.z, (bf16)b.w};
  *reinterpret_cast<bf16x8*>(dst) = v;
}
__device__ __forceinline__ void load8_to_lds(const bf16* src, bf16* dst) {
  *reinterpret_cast<uint4*>(dst) = *reinterpret_cast<const uint4*>(src);
}
__device__ __forceinline__ void store_c(float* p, float v) { *p = v; }
__device__ __forceinline__ void store_c(bf16* p, float v) { *p = (bf16)v; }

// ---------------------------------------------------------------------------
// fp32 -> bf16 cast, 8 elems/thread
// ---------------------------------------------------------------------------
__global__ __launch_bounds__(256) void cast_bf16(const float* __restrict__ s,
                                                 bf16* __restrict__ d) {
  int i = blockIdx.x * 256 + threadIdx.x;
  float4 a = reinterpret_cast<const float4*>(s)[i * 2];
  float4 b = reinterpret_cast<const float4*>(s)[i * 2 + 1];
  bf16x8 v = {(bf16)a.x, (bf16)a.y, (bf16)a.z, (bf16)a.w,
              (bf16)b.x, (bf16)b.y, (bf16)b.z, (bf16)b.w};
  reinterpret_cast<bf16x8*>(d)[i] = v;
}

// ---------------------------------------------------------------------------
// C[M][N] = A[M][K] @ B[N][K]^T   (fp32 accumulate) — unchanged
// ---------------------------------------------------------------------------
template <typename TA, typename TB, typename TC>
__global__ __launch_bounds__(256) void gemm_bt(const TA* __restrict__ A,
                                               const TB* __restrict__ B,
                                               TC* __restrict__ C,
                                               int M, int N, int K) {
  __shared__ __align__(16) bf16 As[128 * 40];
  __shared__ __align__(16) bf16 Bs[128 * 40];

  const int tid  = threadIdx.x;
  const int wave = tid >> 6, lane = tid & 63;
  const int quad = lane >> 4, l16 = lane & 15;
  const int wm = (wave >> 1) * 64, wn = (wave & 1) * 64;
  const int n0 = blockIdx.x * 128, m0 = blockIdx.y * 128;

  const f32x4 zero = {0.f, 0.f, 0.f, 0.f};
  f32x4 acc[4][4];
#pragma unroll
  for (int i = 0; i < 4; ++i)
#pragma unroll
    for (int j = 0; j < 4; ++j) acc[i][j] = zero;

  for (int k0 = 0; k0 < K; k0 += 32) {
#pragma unroll
    for (int it = 0; it < 2; ++it) {
      int linear = it * 2048 + tid * 8;
      int r = linear >> 5, c = linear & 31;
      load8_to_lds(&A[(size_t)(m0 + r) * K + k0 + c], &As[r * 40 + c]);
      load8_to_lds(&B[(size_t)(n0 + r) * K + k0 + c], &Bs[r * 40 + c]);
    }
    __syncthreads();

    bf16x8 af[4], bfr[4];
#pragma unroll
    for (int i = 0; i < 4; ++i)
      af[i] = *reinterpret_cast<const bf16x8*>(&As[(wm + i * 16 + l16) * 40 + quad * 8]);
#pragma unroll
    for (int j = 0; j < 4; ++j)
      bfr[j] = *reinterpret_cast<const bf16x8*>(&Bs[(wn + j * 16 + l16) * 40 + quad * 8]);
#pragma unroll
    for (int i = 0; i < 4; ++i)
#pragma unroll
      for (int j = 0; j < 4; ++j)
        acc[i][j] = mfma16(af[i], bfr[j], acc[i][j]);
    __syncthreads();
  }

#pragma unroll
  for (int i = 0; i < 4; ++i)
#pragma unroll
    for (int j = 0; j < 4; ++j)
#pragma unroll
      for (int r = 0; r < 4; ++r) {
        int row = m0 + wm + i * 16 + quad * 4 + r;
        int col = n0 + wn + j * 16 + l16;
        store_c(&C[(size_t)row * N + col], acc[i][j][r]);
      }
}

// ---------------------------------------------------------------------------
// Per-(token, head) RMS norm + rope — unchanged
// ---------------------------------------------------------------------------
__global__ __launch_bounds__(128) void norm_rope(const bf16* __restrict__ qkv,
                                                 const float* __restrict__ qw,
                                                 const float* __restrict__ kw,
                                                 const int* __restrict__ pos,
                                                 bf16* __restrict__ qn,
                                                 bf16* __restrict__ kn) {
  const int t   = blockIdx.x;
  const int hr  = blockIdx.y;
  const int tid = threadIdx.x;
  const bool isq = hr < 16;
  const int col  = isq ? hr * 128 : 2048 + (hr - 16) * 128;

  float x = (float)qkv[(size_t)t * 4096 + col + tid];
  float ss = x * x;
#pragma unroll
  for (int o = 32; o >= 1; o >>= 1) ss += __shfl_xor(ss, o);
  __shared__ float part[2];
  __shared__ float sh[128];
  if ((tid & 63) == 0) part[tid >> 6] = ss;
  __syncthreads();
  float total = part[0] + part[1];
  float rms = rsqrtf(total * (1.0f / 128.0f) + 1e-6f);
  const float* w = isq ? qw : kw;
  float xn = x * rms * w[tid];
  sh[tid] = xn;
  __syncthreads();

  int d = tid & 63;
  float inv = exp2f((float)d * (-19.93156856932417f / 64.0f));
  float fr = (float)pos[t] * inv;
  float sn, cs;
  sincosf(fr, &sn, &cs);
  float out = (tid < 64) ? (sh[tid] * cs - sh[tid + 64] * sn)
                         : (sh[tid] * cs + sh[tid - 64] * sn);
  if (isq) qn[(size_t)t * 2048 + hr * 128 + tid] = (bf16)out;
  else     kn[(size_t)t * 1024 + (hr - 16) * 128 + tid] = (bf16)out;
}

// ---------------------------------------------------------------------------
// One-time V transpose — unchanged
// ---------------------------------------------------------------------------
__global__ __launch_bounds__(256) void transpose_v(const bf16* __restrict__ qkv,
                                                   bf16* __restrict__ vt) {
  __shared__ __align__(16) bf16 tile[128 * 72];
  const int t0 = blockIdx.x * 64, kvh = blockIdx.y;
  const int tid = threadIdx.x;
#pragma unroll
  for (int it = 0; it < 2; ++it) {
    int linear = it * 4096 + tid * 16;
    int r = linear >> 7, c = linear & 127;
    union { uint4 v; bf16 e[8]; } u0, u1;
    u0.v = *reinterpret_cast<const uint4*>(
        &qkv[(size_t)(t0 + r) * 4096 + 3072 + kvh * 128 + c]);
    u1.v = *reinterpret_cast<const uint4*>(
        &qkv[(size_t)(t0 + r) * 4096 + 3072 + kvh * 128 + c + 8]);
#pragma unroll
    for (int j = 0; j < 8; ++j) tile[(c + j) * 72 + r] = u0.e[j];
#pragma unroll
    for (int j = 0; j < 8; ++j) tile[(c + 8 + j) * 72 + r] = u1.e[j];
  }
  __syncthreads();
#pragma unroll
  for (int it = 0; it < 4; ++it) {
    int linear = it * 2048 + tid * 8;
    int d = linear >> 6, c = linear & 63;
    uint4 v = *reinterpret_cast<const uint4*>(&tile[d * 72 + c]);
    *reinterpret_cast<uint4*>(&vt[(size_t)(kvh * 128 + d) * 4096 + t0 + c]) = v;
  }
}

// ---------------------------------------------------------------------------
// Flash attention v7. grid (32, 16 heads), block 256, one head per block.
// Block bx handles q-tiles {bx, 63-bx} sequentially -> exactly 65 k-tile
// units per block: perfect CU load balance with all 512 blocks resident.
//
// v7: K/V staging via global_load_lds (async DMA) into double-buffered
// LINEAR LDS tiles — eliminates the 32-VGPR register prefetch that the
// v6 build spilled (rocprof: VGPR_Count=80, WRITE_SIZE=733MB vs 16MB of
// real output). DMA stays in vmcnt flight across the compute phase and is
// drained by the single __syncthreads per k-tile (m97 pattern). Linear
// [64][128]-bf16 tiles are a 16..32-way bank conflict on ds_read, so the
// layout is XOR-swizzled (elem x of row r holds src elem x^((r&7)*8)):
// DMA writes linearly to a per-lane PRE-swizzled global source address,
// reads apply the same XOR (both-sides-or-neither rule). 64KB LDS/block
// also caps occupancy at 2 blocks/CU, removing the compiler's incentive
// to shrink VGPRs below the ~130 live and spill.
// ---------------------------------------------------------------------------
__global__ __launch_bounds__(256, 2) void attn(const bf16* __restrict__ q,
                                               const bf16* __restrict__ k,
                                               const bf16* __restrict__ vt,
                                               bf16* __restrict__ out) {
  __shared__ __align__(16) bf16 Ks[2][64 * 128];  // [buf][kv row][dim] swizzled
  __shared__ __align__(16) bf16 Vs[2][128 * 64];  // [buf][dim][kv row] swizzled

  const int head = blockIdx.y, kvh = head >> 1;
  const int bx = blockIdx.x;

  const int tid = threadIdx.x;
  const int wave = tid >> 6, lane = tid & 63;
  const int quad = lane >> 4, l16 = lane & 15;
  const float cExp = 0.08838834764831845f * 1.4426950408889634f; // scale*log2e
  const f32x4 zero = {0.f, 0.f, 0.f, 0.f};

  // ---- per-lane DMA source offsets (elements), pre-swizzled so the linear
  //      LDS write lands in XOR-swizzled layout ----
  // K tile: 64 rows x 128 dims, 16 chunks(16B)/row; lane chunk c=lane&15,
  //         row r = (wave*4+it)*4 + lane/16; src chunk = c ^ (r&7).
  // V tile: 128 rows(dim) x 64 tokens, 8 chunks/row; c=lane&7,
  //         row d = (wave*4+it)*8 + lane/8; src chunk = c ^ (d&7), d&7==lane>>3&7.
  int kSrc[4], vSrc[4];
#pragma unroll
  for (int it = 0; it < 4; ++it) {
    int r = (wave * 4 + it) * 4 + (lane >> 4);
    kSrc[it] = r * 1024 + kvh * 128 + (((lane & 15) ^ (r & 7)) << 3);
    int d = (wave * 4 + it) * 8 + (lane >> 3);
    vSrc[it] = (kvh * 128 + d) * 4096 + (((lane & 7) ^ (lane >> 3)) << 3);
  }

  // ---- read-side swizzled offsets (row&7 == l16&7 for both K and V reads) ----
  const int kswz = (l16 & 7) << 3;
  int koff[4], voff[4];
#pragma unroll
  for (int s = 0; s < 4; ++s) {
    koff[s] = (s * 32 + quad * 8) ^ kswz;  // 16B-aligned within 128-elem row
    voff[s] = (s * 16 + quad * 4) ^ kswz;  // 8B-aligned within 64-elem row
  }

  // ---- prologue: stage phase-0 tile 0 into buffer 0 (async) ----
#pragma unroll
  for (int it = 0; it < 4; ++it) {
    gload_lds16(&k[kSrc[it]], &Ks[0][(wave * 4 + it) * 512]);
    gload_lds16(&vt[vSrc[it]], &Vs[0][(wave * 4 + it) * 512]);
  }
  int cur = 0;

#pragma unroll
  for (int phase = 0; phase < 2; ++phase) {
    const int qt = phase == 0 ? bx : 63 - bx;
    const int q0 = qt * 64;
    const int kend = q0 + 64;
    const int qrow = q0 + wave * 16 + l16;

    // Q fragments: B[n=l16][k=s*32+quad*8+j]
    bf16x8 qf[4];
#pragma unroll
    for (int s = 0; s < 4; ++s)
      qf[s] = *reinterpret_cast<const bf16x8*>(
          &q[(size_t)qrow * 2048 + head * 128 + s * 32 + quad * 8]);

    f32x4 o_acc[8];  // O^T: d = dt*16+quad*4+r, q = l16
#pragma unroll
    for (int dt = 0; dt < 8; ++dt) o_acc[dt] = zero;
    float m_i = -3.0e38f, l_i = 0.f;

    for (int k0 = 0; k0 < kend; k0 += 64) {
      // buf[cur]'s DMA (issued last iter / prologue) is drained by the
      // vmcnt(0) the compiler emits before s_barrier; also all waves are
      // done reading buf[cur^1], so it is free to restage.
      __syncthreads();

      // ---- issue async DMA for next tile (next k0, or phase-1 tile 0);
      //      stays in flight across this tile's compute ----
      int nk0 = -1;
      if (k0 + 64 < kend)     nk0 = k0 + 64;
      else if (phase == 0)    nk0 = 0;
      if (nk0 >= 0) {
#pragma unroll
        for (int it = 0; it < 4; ++it) {
          gload_lds16(&k[kSrc[it] + nk0 * 1024],
                      &Ks[cur ^ 1][(wave * 4 + it) * 512]);
          gload_lds16(&vt[vSrc[it] + nk0],
                      &Vs[cur ^ 1][(wave * 4 + it) * 512]);
        }
      }

      const bf16* KsL = Ks[cur];
      const bf16* VsL = Vs[cur];

      // ---- S^T = K Q^T : rows t (4 tiles of 16), cols q (16) ----
      f32x4 s_acc[4];
#pragma unroll
      for (int mt = 0; mt < 4; ++mt) {
        bf16x8 kf[4];
#pragma unroll
        for (int ks = 0; ks < 4; ++ks)
          kf[ks] = *reinterpret_cast<const bf16x8*>(
              &KsL[(mt * 16 + l16) * 128 + koff[ks]]);
        f32x4 sa = zero;
#pragma unroll
        for (int ks = 0; ks < 4; ++ks) sa = mfma16(kf[ks], qf[ks], sa);
        s_acc[mt] = sa;
      }

      // ---- causal mask (diagonal tile only): t > q -> -inf ----
      if (k0 == q0) {
        int tq = wave * 16 + l16;
#pragma unroll
        for (int mt = 0; mt < 4; ++mt)
#pragma unroll
          for (int r = 0; r < 4; ++r) {
            int tk = mt * 16 + quad * 4 + r;
            if (tk > tq) s_acc[mt][r] = -3.0e38f;
          }
      }

      // ---- online softmax: q fixed per lane (l16); reduce regs + quads ----
      {
        float mx = -3.0e38f;
#pragma unroll
        for (int mt = 0; mt < 4; ++mt)
#pragma unroll
          for (int r = 0; r < 4; ++r) mx = fmaxf(mx, s_acc[mt][r]);
        mx = fmaxf(mx, __shfl_xor(mx, 16));
        mx = fmaxf(mx, __shfl_xor(mx, 32));
        float mn = fmaxf(m_i, mx);
        float al = exp2f((m_i - mn) * cExp);
        m_i = mn;
        float nmc = -mn * cExp;
        float rs = 0.f;
#pragma unroll
        for (int mt = 0; mt < 4; ++mt)
#pragma unroll
          for (int r = 0; r < 4; ++r) {
            float pe = exp2f(fmaf(s_acc[mt][r], cExp, nmc));
            s_acc[mt][r] = pe;
            rs += pe;
          }
        rs += __shfl_xor(rs, 16);
        rs += __shfl_xor(rs, 32);
        l_i = l_i * al + rs;
#pragma unroll
        for (int dt = 0; dt < 8; ++dt)
#pragma unroll
          for (int r = 0; r < 4; ++r) o_acc[dt][r] *= al;
      }

      // ---- pack P in-register: B[k=t=quad*4+j][n=q=l16] per mt ----
      bf16x4 pb[4];
#pragma unroll
      for (int mt = 0; mt < 4; ++mt) {
        bf16x4 t;
#pragma unroll
        for (int r = 0; r < 4; ++r) t[r] = (bf16)s_acc[mt][r];
        pb[mt] = t;
      }

      // ---- O^T += V^T P via chained 16x16x16 ----
#pragma unroll
      for (int dt = 0; dt < 8; ++dt) {
        const bf16* vrow = &VsL[(dt * 16 + l16) * 64];
        bf16x4 va0 = *reinterpret_cast<const bf16x4*>(&vrow[voff[0]]);
        bf16x4 va1 = *reinterpret_cast<const bf16x4*>(&vrow[voff[1]]);
        bf16x4 va2 = *reinterpret_cast<const bf16x4*>(&vrow[voff[2]]);
        bf16x4 va3 = *reinterpret_cast<const bf16x4*>(&vrow[voff[3]]);
        mfma16x16_chain4(va0, va1, va2, va3, pb[0], pb[1], pb[2], pb[3],
                         o_acc[dt]);
      }
      cur ^= 1;
    }

    // ---- epilogue: O = O^T/l, 4 contiguous d per reg-quad ----
    float rl = __builtin_amdgcn_rcpf(l_i);
#pragma unroll
    for (int dt = 0; dt < 8; ++dt) {
      bf16x4 ov;
#pragma unroll
      for (int r = 0; r < 4; ++r) ov[r] = (bf16)(o_acc[dt][r] * rl);
      *reinterpret_cast<bf16x4*>(
          &out[(size_t)qrow * 2048 + head * 128 + dt * 16 + quad * 4]) = ov;
    }
  }
}

// ---------------------------------------------------------------------------
extern "C" void kernel_launch(void* const* d_in, const int* in_sizes, int n_in,
                              void* d_out, int out_size, void* d_ws, size_t ws_size,
                              hipStream_t stream) {
  const float* hidden = (const float*)d_in[0];
  const float* qkv_w  = (const float*)d_in[1];
  const float* qnw    = (const float*)d_in[2];
  const float* knw    = (const float*)d_in[3];
  const float* o_w    = (const float*)d_in[4];
  const int*   pos    = (const int*)d_in[5];

  bf16* qkv = (bf16*)d_ws;                       // 4096*4096
  bf16* qn  = qkv + (size_t)4096 * 4096;         // 4096*2048
  bf16* kn  = qn  + (size_t)4096 * 2048;         // 4096*1024
  bf16* vt  = kn  + (size_t)4096 * 1024;         // 1024*4096
  bf16* ao  = vt  + (size_t)1024 * 4096;         // 4096*2048
  bf16* hb  = ao;   // bf16 hidden, dead before attn writes ao
  bf16* wq  = kn;   // bf16 qkv_w, dead before norm_rope/transpose write kn/vt
  bf16* wo  = qn;   // bf16 o_w, cast after attn (qn dead)
  float* out = (float*)d_out;

  cast_bf16<<<4096, 256, 0, stream>>>(hidden, hb);
  cast_bf16<<<4096, 256, 0, stream>>>(qkv_w, wq);
  gemm_bt<<<dim3(32, 32), 256, 0, stream>>>(hb, wq, qkv, 4096, 4096, 2048);
  norm_rope<<<dim3(4096, 24), 128, 0, stream>>>(qkv, qnw, knw, pos, qn, kn);
  transpose_v<<<dim3(64, 8), 256, 0, stream>>>(qkv, vt);
  attn<<<dim3(32, 16), 256, 0, stream>>>(qn, kn, vt, ao);
  cast_bf16<<<2048, 256, 0, stream>>>(o_w, wo);
  gemm_bt<<<dim3(16, 32), 256, 0, stream>>>(ao, wo, out, 4096, 2048, 2048);
}

// Round 2
// 468.602 us; speedup vs baseline: 1.4896x; 1.0107x over previous
//
#include <hip/hip_runtime.h>
#include <hip/hip_bf16.h>
#include <math.h>

// ---------------------------------------------------------------------------
// Qwen3 attention block: T=4096, HIDDEN=2048, 16 Q heads, 8 KV heads,
// HEAD_DIM=128, rope theta 1e6, rms eps 1e-6, causal.
// fp32 in/out; bf16 internally for MFMA with fp32 accumulation.
//
// ws layout (84 MB, regions reused across phases):
//   qkv  bf16 [4096][4096]  @ 0
//   qn   bf16 [4096][2048]  (also wo after attn)
//   kn   bf16 [4096][1024]  (kn+vt region doubles as wq pre-gemm1)
//   vt   bf16 [1024][4096]
//   ao   bf16 [4096][2048]  (doubles as hb pre-attn)
// ---------------------------------------------------------------------------

typedef __bf16 bf16;
typedef __bf16 bf16x4 __attribute__((ext_vector_type(4)));
typedef __bf16 bf16x8 __attribute__((ext_vector_type(8)));
typedef float  f32x4  __attribute__((ext_vector_type(4)));

__device__ __forceinline__ f32x4 mfma16(bf16x8 a, bf16x8 b, f32x4 c) {
  return __builtin_amdgcn_mfma_f32_16x16x32_bf16(a, b, c, 0, 0, 0);
}

// 4 chained 16x16x16 bf16 MFMAs accumulating into one C/D quad.
// A/B frag [m|n = l16][k = quad*4 + j] == S^T C-layout, so P feeds PV directly
// from registers. Single leading s_nop 2 covers the VALU-write -> MFMA-read
// hazard (same-acc MFMA->MFMA chains are HW-interlocked).
__device__ __forceinline__ void mfma16x16_chain4(const bf16x4& a0, const bf16x4& a1,
                                                 const bf16x4& a2, const bf16x4& a3,
                                                 const bf16x4& b0, const bf16x4& b1,
                                                 const bf16x4& b2, const bf16x4& b3,
                                                 f32x4& c) {
  asm volatile(
      "s_nop 2\n\t"
      "v_mfma_f32_16x16x16_bf16 %0, %1, %5, %0\n\t"
      "v_mfma_f32_16x16x16_bf16 %0, %2, %6, %0\n\t"
      "v_mfma_f32_16x16x16_bf16 %0, %3, %7, %0\n\t"
      "v_mfma_f32_16x16x16_bf16 %0, %4, %8, %0"
      : "+v"(c)
      : "v"(a0), "v"(a1), "v"(a2), "v"(a3),
        "v"(b0), "v"(b1), "v"(b2), "v"(b3));
}

// Async global->LDS DMA, 16B per lane. LDS dest is wave-uniform base +
// lane*16 (hardware rule); global src is per-lane.
__device__ __forceinline__ void gload_lds16(const bf16* g, bf16* l) {
  __builtin_amdgcn_global_load_lds(
      (const __attribute__((address_space(1))) unsigned int*)g,
      (__attribute__((address_space(3))) unsigned int*)l, 16, 0, 0);
}

__device__ __forceinline__ void store_c(float* p, float v) { *p = v; }
__device__ __forceinline__ void store_c(bf16* p, float v) { *p = (bf16)v; }

// ---------------------------------------------------------------------------
// fp32 -> bf16 cast, 8 elems/thread
// ---------------------------------------------------------------------------
__global__ __launch_bounds__(256) void cast_bf16(const float* __restrict__ s,
                                                 bf16* __restrict__ d) {
  int i = blockIdx.x * 256 + threadIdx.x;
  float4 a = reinterpret_cast<const float4*>(s)[i * 2];
  float4 b = reinterpret_cast<const float4*>(s)[i * 2 + 1];
  bf16x8 v = {(bf16)a.x, (bf16)a.y, (bf16)a.z, (bf16)a.w,
              (bf16)b.x, (bf16)b.y, (bf16)b.z, (bf16)b.w};
  reinterpret_cast<bf16x8*>(d)[i] = v;
}

// ---------------------------------------------------------------------------
// C[M][N] = A[M][K] @ B[N][K]^T   (fp32 accumulate)
// v2 (m97 structure): global_load_lds width-16 staging into LINEAR [128][32]
// LDS tiles (no padding -- DMA dest must be contiguous in lane order),
// 2-barrier K-loop. Replaces the register-round-trip staging (m93 rung,
// ~517 TF) with the measured 874-912 TF recipe: staging no longer burns
// VALU slots, loads stay in vmcnt flight until the pre-barrier drain.
// Fragment reads are ds_read_b128 at row stride 64B: a wave64 b128 read
// needs 8 LDS clocks structurally, and the 8 rows/bank-quad pipeline into
// exactly those 8 clocks (m97-verified layout).
// ---------------------------------------------------------------------------
template <typename TC>
__global__ __launch_bounds__(256) void gemm_bt(const bf16* __restrict__ A,
                                               const bf16* __restrict__ B,
                                               TC* __restrict__ C,
                                               int M, int N, int K) {
  __shared__ __align__(16) bf16 As[128 * 32];
  __shared__ __align__(16) bf16 Bs[128 * 32];

  const int tid  = threadIdx.x;
  const int wave = tid >> 6, lane = tid & 63;
  const int quad = lane >> 4, l16 = lane & 15;
  const int wm = (wave >> 1) * 64, wn = (wave & 1) * 64;
  const int n0 = blockIdx.x * 128, m0 = blockIdx.y * 128;

  // staging geometry: iter it covers rows it*64..it*64+63;
  // thread t -> row it*64 + t/4, col (t&3)*8 (16B chunk), LDS elem it*2048+t*8
  const int r0 = tid >> 2;
  const int c0 = (tid & 3) * 8;
  const size_t aBase = (size_t)(m0 + r0) * K + c0;
  const size_t bBase = (size_t)(n0 + r0) * K + c0;

  const f32x4 zero = {0.f, 0.f, 0.f, 0.f};
  f32x4 acc[4][4];
#pragma unroll
  for (int i = 0; i < 4; ++i)
#pragma unroll
    for (int j = 0; j < 4; ++j) acc[i][j] = zero;

  for (int k0 = 0; k0 < K; k0 += 32) {
    gload_lds16(&A[aBase + k0],           &As[tid * 8]);
    gload_lds16(&A[aBase + 64 * (size_t)K + k0], &As[2048 + tid * 8]);
    gload_lds16(&B[bBase + k0],           &Bs[tid * 8]);
    gload_lds16(&B[bBase + 64 * (size_t)K + k0], &Bs[2048 + tid * 8]);
    __syncthreads();  // compiler emits vmcnt(0) drain before s_barrier

    bf16x8 af[4], bfr[4];
#pragma unroll
    for (int i = 0; i < 4; ++i)
      af[i] = *reinterpret_cast<const bf16x8*>(&As[(wm + i * 16 + l16) * 32 + quad * 8]);
#pragma unroll
    for (int j = 0; j < 4; ++j)
      bfr[j] = *reinterpret_cast<const bf16x8*>(&Bs[(wn + j * 16 + l16) * 32 + quad * 8]);
#pragma unroll
    for (int i = 0; i < 4; ++i)
#pragma unroll
      for (int j = 0; j < 4; ++j)
        acc[i][j] = mfma16(af[i], bfr[j], acc[i][j]);
    __syncthreads();
  }

#pragma unroll
  for (int i = 0; i < 4; ++i)
#pragma unroll
    for (int j = 0; j < 4; ++j)
#pragma unroll
      for (int r = 0; r < 4; ++r) {
        int row = m0 + wm + i * 16 + quad * 4 + r;
        int col = n0 + wn + j * 16 + l16;
        store_c(&C[(size_t)row * N + col], acc[i][j][r]);
      }
}

// ---------------------------------------------------------------------------
// Per-(token, head) RMS norm + rope — unchanged
// ---------------------------------------------------------------------------
__global__ __launch_bounds__(128) void norm_rope(const bf16* __restrict__ qkv,
                                                 const float* __restrict__ qw,
                                                 const float* __restrict__ kw,
                                                 const int* __restrict__ pos,
                                                 bf16* __restrict__ qn,
                                                 bf16* __restrict__ kn) {
  const int t   = blockIdx.x;
  const int hr  = blockIdx.y;
  const int tid = threadIdx.x;
  const bool isq = hr < 16;
  const int col  = isq ? hr * 128 : 2048 + (hr - 16) * 128;

  float x = (float)qkv[(size_t)t * 4096 + col + tid];
  float ss = x * x;
#pragma unroll
  for (int o = 32; o >= 1; o >>= 1) ss += __shfl_xor(ss, o);
  __shared__ float part[2];
  __shared__ float sh[128];
  if ((tid & 63) == 0) part[tid >> 6] = ss;
  __syncthreads();
  float total = part[0] + part[1];
  float rms = rsqrtf(total * (1.0f / 128.0f) + 1e-6f);
  const float* w = isq ? qw : kw;
  float xn = x * rms * w[tid];
  sh[tid] = xn;
  __syncthreads();

  int d = tid & 63;
  float inv = exp2f((float)d * (-19.93156856932417f / 64.0f));
  float fr = (float)pos[t] * inv;
  float sn, cs;
  sincosf(fr, &sn, &cs);
  float out = (tid < 64) ? (sh[tid] * cs - sh[tid + 64] * sn)
                         : (sh[tid] * cs + sh[tid - 64] * sn);
  if (isq) qn[(size_t)t * 2048 + hr * 128 + tid] = (bf16)out;
  else     kn[(size_t)t * 1024 + (hr - 16) * 128 + tid] = (bf16)out;
}

// ---------------------------------------------------------------------------
// One-time V transpose — unchanged
// ---------------------------------------------------------------------------
__global__ __launch_bounds__(256) void transpose_v(const bf16* __restrict__ qkv,
                                                   bf16* __restrict__ vt) {
  __shared__ __align__(16) bf16 tile[128 * 72];
  const int t0 = blockIdx.x * 64, kvh = blockIdx.y;
  const int tid = threadIdx.x;
#pragma unroll
  for (int it = 0; it < 2; ++it) {
    int linear = it * 4096 + tid * 16;
    int r = linear >> 7, c = linear & 127;
    union { uint4 v; bf16 e[8]; } u0, u1;
    u0.v = *reinterpret_cast<const uint4*>(
        &qkv[(size_t)(t0 + r) * 4096 + 3072 + kvh * 128 + c]);
    u1.v = *reinterpret_cast<const uint4*>(
        &qkv[(size_t)(t0 + r) * 4096 + 3072 + kvh * 128 + c + 8]);
#pragma unroll
    for (int j = 0; j < 8; ++j) tile[(c + j) * 72 + r] = u0.e[j];
#pragma unroll
    for (int j = 0; j < 8; ++j) tile[(c + 8 + j) * 72 + r] = u1.e[j];
  }
  __syncthreads();
#pragma unroll
  for (int it = 0; it < 4; ++it) {
    int linear = it * 2048 + tid * 8;
    int d = linear >> 6, c = linear & 63;
    uint4 v = *reinterpret_cast<const uint4*>(&tile[d * 72 + c]);
    *reinterpret_cast<uint4*>(&vt[(size_t)(kvh * 128 + d) * 4096 + t0 + c]) = v;
  }
}

// ---------------------------------------------------------------------------
// Flash attention v7 — unchanged from the verified round-1 build.
// grid (32, 16 heads), block 256, one head per block; q-tiles {bx, 63-bx}.
// K/V staged via global_load_lds into double-buffered XOR-swizzled linear
// LDS (pre-swizzled global source, swizzled reads — both-sides rule).
// ---------------------------------------------------------------------------
__global__ __launch_bounds__(256, 2) void attn(const bf16* __restrict__ q,
                                               const bf16* __restrict__ k,
                                               const bf16* __restrict__ vt,
                                               bf16* __restrict__ out) {
  __shared__ __align__(16) bf16 Ks[2][64 * 128];  // [buf][kv row][dim] swizzled
  __shared__ __align__(16) bf16 Vs[2][128 * 64];  // [buf][dim][kv row] swizzled

  const int head = blockIdx.y, kvh = head >> 1;
  const int bx = blockIdx.x;

  const int tid = threadIdx.x;
  const int wave = tid >> 6, lane = tid & 63;
  const int quad = lane >> 4, l16 = lane & 15;
  const float cExp = 0.08838834764831845f * 1.4426950408889634f; // scale*log2e
  const f32x4 zero = {0.f, 0.f, 0.f, 0.f};

  // per-lane DMA source offsets (elements), pre-swizzled so the linear
  // LDS write lands in XOR-swizzled layout
  int kSrc[4], vSrc[4];
#pragma unroll
  for (int it = 0; it < 4; ++it) {
    int r = (wave * 4 + it) * 4 + (lane >> 4);
    kSrc[it] = r * 1024 + kvh * 128 + (((lane & 15) ^ (r & 7)) << 3);
    int d = (wave * 4 + it) * 8 + (lane >> 3);
    vSrc[it] = (kvh * 128 + d) * 4096 + (((lane & 7) ^ (lane >> 3)) << 3);
  }

  // read-side swizzled offsets (row&7 == l16&7 for both K and V reads)
  const int kswz = (l16 & 7) << 3;
  int koff[4], voff[4];
#pragma unroll
  for (int s = 0; s < 4; ++s) {
    koff[s] = (s * 32 + quad * 8) ^ kswz;  // 16B-aligned within 128-elem row
    voff[s] = (s * 16 + quad * 4) ^ kswz;  // 8B-aligned within 64-elem row
  }

  // prologue: stage phase-0 tile 0 into buffer 0 (async)
#pragma unroll
  for (int it = 0; it < 4; ++it) {
    gload_lds16(&k[kSrc[it]], &Ks[0][(wave * 4 + it) * 512]);
    gload_lds16(&vt[vSrc[it]], &Vs[0][(wave * 4 + it) * 512]);
  }
  int cur = 0;

#pragma unroll
  for (int phase = 0; phase < 2; ++phase) {
    const int qt = phase == 0 ? bx : 63 - bx;
    const int q0 = qt * 64;
    const int kend = q0 + 64;
    const int qrow = q0 + wave * 16 + l16;

    // Q fragments: B[n=l16][k=s*32+quad*8+j]
    bf16x8 qf[4];
#pragma unroll
    for (int s = 0; s < 4; ++s)
      qf[s] = *reinterpret_cast<const bf16x8*>(
          &q[(size_t)qrow * 2048 + head * 128 + s * 32 + quad * 8]);

    f32x4 o_acc[8];  // O^T: d = dt*16+quad*4+r, q = l16
#pragma unroll
    for (int dt = 0; dt < 8; ++dt) o_acc[dt] = zero;
    float m_i = -3.0e38f, l_i = 0.f;

    for (int k0 = 0; k0 < kend; k0 += 64) {
      // buf[cur]'s DMA (issued last iter / prologue) is drained by the
      // vmcnt(0) the compiler emits before s_barrier; also all waves are
      // done reading buf[cur^1], so it is free to restage.
      __syncthreads();

      // issue async DMA for next tile (next k0, or phase-1 tile 0);
      // stays in flight across this tile's compute
      int nk0 = -1;
      if (k0 + 64 < kend)     nk0 = k0 + 64;
      else if (phase == 0)    nk0 = 0;
      if (nk0 >= 0) {
#pragma unroll
        for (int it = 0; it < 4; ++it) {
          gload_lds16(&k[kSrc[it] + nk0 * 1024],
                      &Ks[cur ^ 1][(wave * 4 + it) * 512]);
          gload_lds16(&vt[vSrc[it] + nk0],
                      &Vs[cur ^ 1][(wave * 4 + it) * 512]);
        }
      }

      const bf16* KsL = Ks[cur];
      const bf16* VsL = Vs[cur];

      // ---- S^T = K Q^T : rows t (4 tiles of 16), cols q (16) ----
      f32x4 s_acc[4];
#pragma unroll
      for (int mt = 0; mt < 4; ++mt) {
        bf16x8 kf[4];
#pragma unroll
        for (int ks = 0; ks < 4; ++ks)
          kf[ks] = *reinterpret_cast<const bf16x8*>(
              &KsL[(mt * 16 + l16) * 128 + koff[ks]]);
        f32x4 sa = zero;
#pragma unroll
        for (int ks = 0; ks < 4; ++ks) sa = mfma16(kf[ks], qf[ks], sa);
        s_acc[mt] = sa;
      }

      // ---- causal mask (diagonal tile only): t > q -> -inf ----
      if (k0 == q0) {
        int tq = wave * 16 + l16;
#pragma unroll
        for (int mt = 0; mt < 4; ++mt)
#pragma unroll
          for (int r = 0; r < 4; ++r) {
            int tk = mt * 16 + quad * 4 + r;
            if (tk > tq) s_acc[mt][r] = -3.0e38f;
          }
      }

      // ---- online softmax: q fixed per lane (l16); reduce regs + quads ----
      {
        float mx = -3.0e38f;
#pragma unroll
        for (int mt = 0; mt < 4; ++mt)
#pragma unroll
          for (int r = 0; r < 4; ++r) mx = fmaxf(mx, s_acc[mt][r]);
        mx = fmaxf(mx, __shfl_xor(mx, 16));
        mx = fmaxf(mx, __shfl_xor(mx, 32));
        float mn = fmaxf(m_i, mx);
        float al = exp2f((m_i - mn) * cExp);
        m_i = mn;
        float nmc = -mn * cExp;
        float rs = 0.f;
#pragma unroll
        for (int mt = 0; mt < 4; ++mt)
#pragma unroll
          for (int r = 0; r < 4; ++r) {
            float pe = exp2f(fmaf(s_acc[mt][r], cExp, nmc));
            s_acc[mt][r] = pe;
            rs += pe;
          }
        rs += __shfl_xor(rs, 16);
        rs += __shfl_xor(rs, 32);
        l_i = l_i * al + rs;
#pragma unroll
        for (int dt = 0; dt < 8; ++dt)
#pragma unroll
          for (int r = 0; r < 4; ++r) o_acc[dt][r] *= al;
      }

      // ---- pack P in-register: B[k=t=quad*4+j][n=q=l16] per mt ----
      bf16x4 pb[4];
#pragma unroll
      for (int mt = 0; mt < 4; ++mt) {
        bf16x4 t;
#pragma unroll
        for (int r = 0; r < 4; ++r) t[r] = (bf16)s_acc[mt][r];
        pb[mt] = t;
      }

      // ---- O^T += V^T P via chained 16x16x16 ----
#pragma unroll
      for (int dt = 0; dt < 8; ++dt) {
        const bf16* vrow = &VsL[(dt * 16 + l16) * 64];
        bf16x4 va0 = *reinterpret_cast<const bf16x4*>(&vrow[voff[0]]);
        bf16x4 va1 = *reinterpret_cast<const bf16x4*>(&vrow[voff[1]]);
        bf16x4 va2 = *reinterpret_cast<const bf16x4*>(&vrow[voff[2]]);
        bf16x4 va3 = *reinterpret_cast<const bf16x4*>(&vrow[voff[3]]);
        mfma16x16_chain4(va0, va1, va2, va3, pb[0], pb[1], pb[2], pb[3],
                         o_acc[dt]);
      }
      cur ^= 1;
    }

    // ---- epilogue: O = O^T/l, 4 contiguous d per reg-quad ----
    float rl = __builtin_amdgcn_rcpf(l_i);
#pragma unroll
    for (int dt = 0; dt < 8; ++dt) {
      bf16x4 ov;
#pragma unroll
      for (int r = 0; r < 4; ++r) ov[r] = (bf16)(o_acc[dt][r] * rl);
      *reinterpret_cast<bf16x4*>(
          &out[(size_t)qrow * 2048 + head * 128 + dt * 16 + quad * 4]) = ov;
    }
  }
}

// ---------------------------------------------------------------------------
extern "C" void kernel_launch(void* const* d_in, const int* in_sizes, int n_in,
                              void* d_out, int out_size, void* d_ws, size_t ws_size,
                              hipStream_t stream) {
  const float* hidden = (const float*)d_in[0];
  const float* qkv_w  = (const float*)d_in[1];
  const float* qnw    = (const float*)d_in[2];
  const float* knw    = (const float*)d_in[3];
  const float* o_w    = (const float*)d_in[4];
  const int*   pos    = (const int*)d_in[5];

  bf16* qkv = (bf16*)d_ws;                       // 4096*4096
  bf16* qn  = qkv + (size_t)4096 * 4096;         // 4096*2048
  bf16* kn  = qn  + (size_t)4096 * 2048;         // 4096*1024
  bf16* vt  = kn  + (size_t)4096 * 1024;         // 1024*4096
  bf16* ao  = vt  + (size_t)1024 * 4096;         // 4096*2048
  bf16* hb  = ao;   // bf16 hidden, dead before attn writes ao
  bf16* wq  = kn;   // bf16 qkv_w, dead before norm_rope/transpose write kn/vt
  bf16* wo  = qn;   // bf16 o_w, cast after attn (qn dead)
  float* out = (float*)d_out;

  cast_bf16<<<4096, 256, 0, stream>>>(hidden, hb);
  cast_bf16<<<4096, 256, 0, stream>>>(qkv_w, wq);
  gemm_bt<<<dim3(32, 32), 256, 0, stream>>>(hb, wq, qkv, 4096, 4096, 2048);
  norm_rope<<<dim3(4096, 24), 128, 0, stream>>>(qkv, qnw, knw, pos, qn, kn);
  transpose_v<<<dim3(64, 8), 256, 0, stream>>>(qkv, vt);
  attn<<<dim3(32, 16), 256, 0, stream>>>(qn, kn, vt, ao);
  cast_bf16<<<2048, 256, 0, stream>>>(o_w, wo);
  gemm_bt<<<dim3(16, 32), 256, 0, stream>>>(ao, wo, out, 4096, 2048, 2048);
}

// Round 3
// 426.443 us; speedup vs baseline: 1.6368x; 1.0989x over previous
//
#include <hip/hip_runtime.h>
#include <hip/hip_bf16.h>
#include <math.h>

// ---------------------------------------------------------------------------
// Qwen3 attention block: T=4096, HIDDEN=2048, 16 Q heads, 8 KV heads,
// HEAD_DIM=128, rope theta 1e6, rms eps 1e-6, causal.
// fp32 in/out; bf16 internally for MFMA with fp32 accumulation.
//
// ws layout (84 MB, regions reused across phases):
//   qkv  bf16 [4096][4096]  @ 0
//   qn   bf16 [4096][2048]  (also wo after attn)
//   kn   bf16 [4096][1024]  (kn+vt region doubles as wq pre-gemm1)
//   vt   bf16 [1024][4096]
//   ao   bf16 [4096][2048]  (doubles as hb pre-attn)
// ---------------------------------------------------------------------------

typedef __bf16 bf16;
typedef __bf16 bf16x4 __attribute__((ext_vector_type(4)));
typedef __bf16 bf16x8 __attribute__((ext_vector_type(8)));
typedef float  f32x4  __attribute__((ext_vector_type(4)));

__device__ __forceinline__ f32x4 mfma16(bf16x8 a, bf16x8 b, f32x4 c) {
  return __builtin_amdgcn_mfma_f32_16x16x32_bf16(a, b, c, 0, 0, 0);
}

// 4 chained 16x16x16 bf16 MFMAs accumulating into one C/D quad.
__device__ __forceinline__ void mfma16x16_chain4(const bf16x4& a0, const bf16x4& a1,
                                                 const bf16x4& a2, const bf16x4& a3,
                                                 const bf16x4& b0, const bf16x4& b1,
                                                 const bf16x4& b2, const bf16x4& b3,
                                                 f32x4& c) {
  asm volatile(
      "s_nop 2\n\t"
      "v_mfma_f32_16x16x16_bf16 %0, %1, %5, %0\n\t"
      "v_mfma_f32_16x16x16_bf16 %0, %2, %6, %0\n\t"
      "v_mfma_f32_16x16x16_bf16 %0, %3, %7, %0\n\t"
      "v_mfma_f32_16x16x16_bf16 %0, %4, %8, %0"
      : "+v"(c)
      : "v"(a0), "v"(a1), "v"(a2), "v"(a3),
        "v"(b0), "v"(b1), "v"(b2), "v"(b3));
}

// Async global->LDS DMA, 16B per lane. LDS dest is wave-uniform base +
// lane*16 (hardware rule); global src is per-lane.
__device__ __forceinline__ void gload_lds16(const bf16* g, bf16* l) {
  __builtin_amdgcn_global_load_lds(
      (const __attribute__((address_space(1))) unsigned int*)g,
      (__attribute__((address_space(3))) unsigned int*)l, 16, 0, 0);
}

__device__ __forceinline__ void store_c(float* p, float v) { *p = v; }
__device__ __forceinline__ void store_c(bf16* p, float v) { *p = (bf16)v; }

// ---------------------------------------------------------------------------
// fp32 -> bf16 cast, 8 elems/thread
// ---------------------------------------------------------------------------
__global__ __launch_bounds__(256) void cast_bf16(const float* __restrict__ s,
                                                 bf16* __restrict__ d) {
  int i = blockIdx.x * 256 + threadIdx.x;
  float4 a = reinterpret_cast<const float4*>(s)[i * 2];
  float4 b = reinterpret_cast<const float4*>(s)[i * 2 + 1];
  bf16x8 v = {(bf16)a.x, (bf16)a.y, (bf16)a.z, (bf16)a.w,
              (bf16)b.x, (bf16)b.y, (bf16)b.z, (bf16)b.w};
  reinterpret_cast<bf16x8*>(d)[i] = v;
}

// ---------------------------------------------------------------------------
// C[M][N] = A[M][K] @ B[N][K]^T   (fp32 accumulate)
// v3: (a) __launch_bounds__(256, 4): min 4 waves/EU -> 128-VGPR budget.
//     Live state is ~116 VGPRs (acc 64 + frags 32 + addr); the bare
//     __launch_bounds__(256) default targets 6 waves/EU (84 VGPRs) and
//     spills -- the R0 attn failure mode, and why the R2 m97 port was
//     neutral (old and new structure both spill-bound at ~520 TF).
// (b) T3-minimum 2-phase double-buffer (guide 5.5 recipe): stage K-step
//     t+1 into buf[cur^1] BEFORE computing buf[cur]; ONE __syncthreads
//     per K-step (its vmcnt(0)+lgkmcnt(0) drain makes the handoff
//     race-free by construction). DMA latency hides under the 16 MFMAs
//     instead of being exposed between stage and barrier.
// ---------------------------------------------------------------------------
__device__ __forceinline__ void gemm_step(const bf16* AsL, const bf16* BsL,
                                          int wm, int wn, int l16, int quad,
                                          f32x4 (&acc)[4][4]) {
  bf16x8 af[4], bfr[4];
#pragma unroll
  for (int i = 0; i < 4; ++i)
    af[i] = *reinterpret_cast<const bf16x8*>(&AsL[(wm + i * 16 + l16) * 32 + quad * 8]);
#pragma unroll
  for (int j = 0; j < 4; ++j)
    bfr[j] = *reinterpret_cast<const bf16x8*>(&BsL[(wn + j * 16 + l16) * 32 + quad * 8]);
#pragma unroll
  for (int i = 0; i < 4; ++i)
#pragma unroll
    for (int j = 0; j < 4; ++j)
      acc[i][j] = mfma16(af[i], bfr[j], acc[i][j]);
}

template <typename TC>
__global__ __launch_bounds__(256, 4) void gemm_bt(const bf16* __restrict__ A,
                                                  const bf16* __restrict__ B,
                                                  TC* __restrict__ C,
                                                  int M, int N, int K) {
  __shared__ __align__(16) bf16 As[2][128 * 32];
  __shared__ __align__(16) bf16 Bs[2][128 * 32];

  const int tid  = threadIdx.x;
  const int wave = tid >> 6, lane = tid & 63;
  const int quad = lane >> 4, l16 = lane & 15;
  const int wm = (wave >> 1) * 64, wn = (wave & 1) * 64;
  const int n0 = blockIdx.x * 128, m0 = blockIdx.y * 128;

  // staging: thread t -> row t/4 (+64 for 2nd DMA), 16B chunk (t&3)*8
  const int r0 = tid >> 2;
  const int c0 = (tid & 3) * 8;
  const size_t aBase = (size_t)(m0 + r0) * K + c0;
  const size_t bBase = (size_t)(n0 + r0) * K + c0;
  const size_t rowK64 = (size_t)64 * K;

  const f32x4 zero = {0.f, 0.f, 0.f, 0.f};
  f32x4 acc[4][4];
#pragma unroll
  for (int i = 0; i < 4; ++i)
#pragma unroll
    for (int j = 0; j < 4; ++j) acc[i][j] = zero;

  // prologue: stage K-step 0 into buf 0
  gload_lds16(&A[aBase],          &As[0][tid * 8]);
  gload_lds16(&A[aBase + rowK64], &As[0][2048 + tid * 8]);
  gload_lds16(&B[bBase],          &Bs[0][tid * 8]);
  gload_lds16(&B[bBase + rowK64], &Bs[0][2048 + tid * 8]);
  __syncthreads();

  int cur = 0;
  for (int k0 = 32; k0 < K; k0 += 32) {
    const int nb = cur ^ 1;
    // stage next K-step (async; in flight across this step's compute).
    // buf[nb] was last read two steps ago and drained by that step's barrier.
    gload_lds16(&A[aBase + k0],          &As[nb][tid * 8]);
    gload_lds16(&A[aBase + rowK64 + k0], &As[nb][2048 + tid * 8]);
    gload_lds16(&B[bBase + k0],          &Bs[nb][tid * 8]);
    gload_lds16(&B[bBase + rowK64 + k0], &Bs[nb][2048 + tid * 8]);

    gemm_step(As[cur], Bs[cur], wm, wn, l16, quad, acc);

    __syncthreads();  // drains vmcnt (DMA landed) + lgkm; all waves done reading
    cur = nb;
  }
  gemm_step(As[cur], Bs[cur], wm, wn, l16, quad, acc);

#pragma unroll
  for (int i = 0; i < 4; ++i)
#pragma unroll
    for (int j = 0; j < 4; ++j)
#pragma unroll
      for (int r = 0; r < 4; ++r) {
        int row = m0 + wm + i * 16 + quad * 4 + r;
        int col = n0 + wn + j * 16 + l16;
        store_c(&C[(size_t)row * N + col], acc[i][j][r]);
      }
}

// ---------------------------------------------------------------------------
// Per-(token, head) RMS norm + rope — unchanged
// ---------------------------------------------------------------------------
__global__ __launch_bounds__(128) void norm_rope(const bf16* __restrict__ qkv,
                                                 const float* __restrict__ qw,
                                                 const float* __restrict__ kw,
                                                 const int* __restrict__ pos,
                                                 bf16* __restrict__ qn,
                                                 bf16* __restrict__ kn) {
  const int t   = blockIdx.x;
  const int hr  = blockIdx.y;
  const int tid = threadIdx.x;
  const bool isq = hr < 16;
  const int col  = isq ? hr * 128 : 2048 + (hr - 16) * 128;

  float x = (float)qkv[(size_t)t * 4096 + col + tid];
  float ss = x * x;
#pragma unroll
  for (int o = 32; o >= 1; o >>= 1) ss += __shfl_xor(ss, o);
  __shared__ float part[2];
  __shared__ float sh[128];
  if ((tid & 63) == 0) part[tid >> 6] = ss;
  __syncthreads();
  float total = part[0] + part[1];
  float rms = rsqrtf(total * (1.0f / 128.0f) + 1e-6f);
  const float* w = isq ? qw : kw;
  float xn = x * rms * w[tid];
  sh[tid] = xn;
  __syncthreads();

  int d = tid & 63;
  float inv = exp2f((float)d * (-19.93156856932417f / 64.0f));
  float fr = (float)pos[t] * inv;
  float sn, cs;
  sincosf(fr, &sn, &cs);
  float out = (tid < 64) ? (sh[tid] * cs - sh[tid + 64] * sn)
                         : (sh[tid] * cs + sh[tid - 64] * sn);
  if (isq) qn[(size_t)t * 2048 + hr * 128 + tid] = (bf16)out;
  else     kn[(size_t)t * 1024 + (hr - 16) * 128 + tid] = (bf16)out;
}

// ---------------------------------------------------------------------------
// One-time V transpose — unchanged
// ---------------------------------------------------------------------------
__global__ __launch_bounds__(256) void transpose_v(const bf16* __restrict__ qkv,
                                                   bf16* __restrict__ vt) {
  __shared__ __align__(16) bf16 tile[128 * 72];
  const int t0 = blockIdx.x * 64, kvh = blockIdx.y;
  const int tid = threadIdx.x;
#pragma unroll
  for (int it = 0; it < 2; ++it) {
    int linear = it * 4096 + tid * 16;
    int r = linear >> 7, c = linear & 127;
    union { uint4 v; bf16 e[8]; } u0, u1;
    u0.v = *reinterpret_cast<const uint4*>(
        &qkv[(size_t)(t0 + r) * 4096 + 3072 + kvh * 128 + c]);
    u1.v = *reinterpret_cast<const uint4*>(
        &qkv[(size_t)(t0 + r) * 4096 + 3072 + kvh * 128 + c + 8]);
#pragma unroll
    for (int j = 0; j < 8; ++j) tile[(c + j) * 72 + r] = u0.e[j];
#pragma unroll
    for (int j = 0; j < 8; ++j) tile[(c + 8 + j) * 72 + r] = u1.e[j];
  }
  __syncthreads();
#pragma unroll
  for (int it = 0; it < 4; ++it) {
    int linear = it * 2048 + tid * 8;
    int d = linear >> 6, c = linear & 63;
    uint4 v = *reinterpret_cast<const uint4*>(&tile[d * 72 + c]);
    *reinterpret_cast<uint4*>(&vt[(size_t)(kvh * 128 + d) * 4096 + t0 + c]) = v;
  }
}

// ---------------------------------------------------------------------------
// Flash attention v8. Structure = verified v7 (DMA-staged XOR-swizzled
// double-buffered K/V) plus:
//   - T5 setprio(1) around QK^T and PV MFMA clusters (m191: helps when
//     independent blocks share a CU -- our 2 blocks/CU regime).
//   - T13 defer-max: skip the O-rescale + max update when the tile max
//     grew by <= 8 exp2-units for all lanes (HK THR=8; P bounded by 2^8,
//     f32 accum has headroom; m239 refcheck'd).
// ---------------------------------------------------------------------------
__global__ __launch_bounds__(256, 2) void attn(const bf16* __restrict__ q,
                                               const bf16* __restrict__ k,
                                               const bf16* __restrict__ vt,
                                               bf16* __restrict__ out) {
  __shared__ __align__(16) bf16 Ks[2][64 * 128];  // [buf][kv row][dim] swizzled
  __shared__ __align__(16) bf16 Vs[2][128 * 64];  // [buf][dim][kv row] swizzled

  const int head = blockIdx.y, kvh = head >> 1;
  const int bx = blockIdx.x;

  const int tid = threadIdx.x;
  const int wave = tid >> 6, lane = tid & 63;
  const int quad = lane >> 4, l16 = lane & 15;
  const float cExp = 0.08838834764831845f * 1.4426950408889634f; // scale*log2e
  const f32x4 zero = {0.f, 0.f, 0.f, 0.f};

  // per-lane DMA source offsets (elements), pre-swizzled so the linear
  // LDS write lands in XOR-swizzled layout
  int kSrc[4], vSrc[4];
#pragma unroll
  for (int it = 0; it < 4; ++it) {
    int r = (wave * 4 + it) * 4 + (lane >> 4);
    kSrc[it] = r * 1024 + kvh * 128 + (((lane & 15) ^ (r & 7)) << 3);
    int d = (wave * 4 + it) * 8 + (lane >> 3);
    vSrc[it] = (kvh * 128 + d) * 4096 + (((lane & 7) ^ (lane >> 3)) << 3);
  }

  // read-side swizzled offsets (row&7 == l16&7 for both K and V reads)
  const int kswz = (l16 & 7) << 3;
  int koff[4], voff[4];
#pragma unroll
  for (int s = 0; s < 4; ++s) {
    koff[s] = (s * 32 + quad * 8) ^ kswz;  // 16B-aligned within 128-elem row
    voff[s] = (s * 16 + quad * 4) ^ kswz;  // 8B-aligned within 64-elem row
  }

  // prologue: stage phase-0 tile 0 into buffer 0 (async)
#pragma unroll
  for (int it = 0; it < 4; ++it) {
    gload_lds16(&k[kSrc[it]], &Ks[0][(wave * 4 + it) * 512]);
    gload_lds16(&vt[vSrc[it]], &Vs[0][(wave * 4 + it) * 512]);
  }
  int cur = 0;

#pragma unroll
  for (int phase = 0; phase < 2; ++phase) {
    const int qt = phase == 0 ? bx : 63 - bx;
    const int q0 = qt * 64;
    const int kend = q0 + 64;
    const int qrow = q0 + wave * 16 + l16;

    // Q fragments: B[n=l16][k=s*32+quad*8+j]
    bf16x8 qf[4];
#pragma unroll
    for (int s = 0; s < 4; ++s)
      qf[s] = *reinterpret_cast<const bf16x8*>(
          &q[(size_t)qrow * 2048 + head * 128 + s * 32 + quad * 8]);

    f32x4 o_acc[8];  // O^T: d = dt*16+quad*4+r, q = l16
#pragma unroll
    for (int dt = 0; dt < 8; ++dt) o_acc[dt] = zero;
    float m_i = -3.0e38f, l_i = 0.f;

    for (int k0 = 0; k0 < kend; k0 += 64) {
      // buf[cur]'s DMA (issued last iter / prologue) is drained by the
      // vmcnt(0) the compiler emits before s_barrier; also all waves are
      // done reading buf[cur^1], so it is free to restage.
      __syncthreads();

      // issue async DMA for next tile (next k0, or phase-1 tile 0);
      // stays in flight across this tile's compute
      int nk0 = -1;
      if (k0 + 64 < kend)     nk0 = k0 + 64;
      else if (phase == 0)    nk0 = 0;
      if (nk0 >= 0) {
#pragma unroll
        for (int it = 0; it < 4; ++it) {
          gload_lds16(&k[kSrc[it] + nk0 * 1024],
                      &Ks[cur ^ 1][(wave * 4 + it) * 512]);
          gload_lds16(&vt[vSrc[it] + nk0],
                      &Vs[cur ^ 1][(wave * 4 + it) * 512]);
        }
      }

      const bf16* KsL = Ks[cur];
      const bf16* VsL = Vs[cur];

      // ---- S^T = K Q^T : rows t (4 tiles of 16), cols q (16) ----
      f32x4 s_acc[4];
      __builtin_amdgcn_s_setprio(1);
#pragma unroll
      for (int mt = 0; mt < 4; ++mt) {
        bf16x8 kf[4];
#pragma unroll
        for (int ks = 0; ks < 4; ++ks)
          kf[ks] = *reinterpret_cast<const bf16x8*>(
              &KsL[(mt * 16 + l16) * 128 + koff[ks]]);
        f32x4 sa = zero;
#pragma unroll
        for (int ks = 0; ks < 4; ++ks) sa = mfma16(kf[ks], qf[ks], sa);
        s_acc[mt] = sa;
      }
      __builtin_amdgcn_s_setprio(0);

      // ---- causal mask (diagonal tile only): t > q -> -inf ----
      if (k0 == q0) {
        int tq = wave * 16 + l16;
#pragma unroll
        for (int mt = 0; mt < 4; ++mt)
#pragma unroll
          for (int r = 0; r < 4; ++r) {
            int tk = mt * 16 + quad * 4 + r;
            if (tk > tq) s_acc[mt][r] = -3.0e38f;
          }
      }

      // ---- online softmax with defer-max (T13) ----
      {
        float mx = -3.0e38f;
#pragma unroll
        for (int mt = 0; mt < 4; ++mt)
#pragma unroll
          for (int r = 0; r < 4; ++r) mx = fmaxf(mx, s_acc[mt][r]);
        mx = fmaxf(mx, __shfl_xor(mx, 16));
        mx = fmaxf(mx, __shfl_xor(mx, 32));
        // fast path: max grew by <= 8 exp2-units for every lane -> keep m_i,
        // skip alpha + O-rescale (P entries bounded by 2^8, f32 acc is fine)
        if (!__all((mx - m_i) * cExp <= 8.0f)) {
          float mn = fmaxf(m_i, mx);
          float al = exp2f((m_i - mn) * cExp);
          m_i = mn;
          l_i *= al;
#pragma unroll
          for (int dt = 0; dt < 8; ++dt)
#pragma unroll
            for (int r = 0; r < 4; ++r) o_acc[dt][r] *= al;
        }
        float nmc = -m_i * cExp;
        float rs = 0.f;
#pragma unroll
        for (int mt = 0; mt < 4; ++mt)
#pragma unroll
          for (int r = 0; r < 4; ++r) {
            float pe = exp2f(fmaf(s_acc[mt][r], cExp, nmc));
            s_acc[mt][r] = pe;
            rs += pe;
          }
        rs += __shfl_xor(rs, 16);
        rs += __shfl_xor(rs, 32);
        l_i += rs;
      }

      // ---- pack P in-register: B[k=t=quad*4+j][n=q=l16] per mt ----
      bf16x4 pb[4];
#pragma unroll
      for (int mt = 0; mt < 4; ++mt) {
        bf16x4 t;
#pragma unroll
        for (int r = 0; r < 4; ++r) t[r] = (bf16)s_acc[mt][r];
        pb[mt] = t;
      }

      // ---- O^T += V^T P via chained 16x16x16 ----
      __builtin_amdgcn_s_setprio(1);
#pragma unroll
      for (int dt = 0; dt < 8; ++dt) {
        const bf16* vrow = &VsL[(dt * 16 + l16) * 64];
        bf16x4 va0 = *reinterpret_cast<const bf16x4*>(&vrow[voff[0]]);
        bf16x4 va1 = *reinterpret_cast<const bf16x4*>(&vrow[voff[1]]);
        bf16x4 va2 = *reinterpret_cast<const bf16x4*>(&vrow[voff[2]]);
        bf16x4 va3 = *reinterpret_cast<const bf16x4*>(&vrow[voff[3]]);
        mfma16x16_chain4(va0, va1, va2, va3, pb[0], pb[1], pb[2], pb[3],
                         o_acc[dt]);
      }
      __builtin_amdgcn_s_setprio(0);
      cur ^= 1;
    }

    // ---- epilogue: O = O^T/l, 4 contiguous d per reg-quad ----
    float rl = __builtin_amdgcn_rcpf(l_i);
#pragma unroll
    for (int dt = 0; dt < 8; ++dt) {
      bf16x4 ov;
#pragma unroll
      for (int r = 0; r < 4; ++r) ov[r] = (bf16)(o_acc[dt][r] * rl);
      *reinterpret_cast<bf16x4*>(
          &out[(size_t)qrow * 2048 + head * 128 + dt * 16 + quad * 4]) = ov;
    }
  }
}

// ---------------------------------------------------------------------------
extern "C" void kernel_launch(void* const* d_in, const int* in_sizes, int n_in,
                              void* d_out, int out_size, void* d_ws, size_t ws_size,
                              hipStream_t stream) {
  const float* hidden = (const float*)d_in[0];
  const float* qkv_w  = (const float*)d_in[1];
  const float* qnw    = (const float*)d_in[2];
  const float* knw    = (const float*)d_in[3];
  const float* o_w    = (const float*)d_in[4];
  const int*   pos    = (const int*)d_in[5];

  bf16* qkv = (bf16*)d_ws;                       // 4096*4096
  bf16* qn  = qkv + (size_t)4096 * 4096;         // 4096*2048
  bf16* kn  = qn  + (size_t)4096 * 2048;         // 4096*1024
  bf16* vt  = kn  + (size_t)4096 * 1024;         // 1024*4096
  bf16* ao  = vt  + (size_t)1024 * 4096;         // 4096*2048
  bf16* hb  = ao;   // bf16 hidden, dead before attn writes ao
  bf16* wq  = kn;   // bf16 qkv_w, dead before norm_rope/transpose write kn/vt
  bf16* wo  = qn;   // bf16 o_w, cast after attn (qn dead)
  float* out = (float*)d_out;

  cast_bf16<<<4096, 256, 0, stream>>>(hidden, hb);
  cast_bf16<<<4096, 256, 0, stream>>>(qkv_w, wq);
  gemm_bt<<<dim3(32, 32), 256, 0, stream>>>(hb, wq, qkv, 4096, 4096, 2048);
  norm_rope<<<dim3(4096, 24), 128, 0, stream>>>(qkv, qnw, knw, pos, qn, kn);
  transpose_v<<<dim3(64, 8), 256, 0, stream>>>(qkv, vt);
  attn<<<dim3(32, 16), 256, 0, stream>>>(qn, kn, vt, ao);
  cast_bf16<<<2048, 256, 0, stream>>>(o_w, wo);
  gemm_bt<<<dim3(16, 32), 256, 0, stream>>>(ao, wo, out, 4096, 2048, 2048);
}

// Round 4
// 417.401 us; speedup vs baseline: 1.6723x; 1.0217x over previous
//
#include <hip/hip_runtime.h>
#include <hip/hip_bf16.h>
#include <math.h>

// ---------------------------------------------------------------------------
// Qwen3 attention block: T=4096, HIDDEN=2048, 16 Q heads, 8 KV heads,
// HEAD_DIM=128, rope theta 1e6, rms eps 1e-6, causal.
// fp32 in/out; bf16 internally for MFMA with fp32 accumulation.
// ---------------------------------------------------------------------------

typedef __bf16 bf16;
typedef __bf16 bf16x4 __attribute__((ext_vector_type(4)));
typedef __bf16 bf16x8 __attribute__((ext_vector_type(8)));
typedef float  f32x4  __attribute__((ext_vector_type(4)));

__device__ __forceinline__ f32x4 mfma16(bf16x8 a, bf16x8 b, f32x4 c) {
  return __builtin_amdgcn_mfma_f32_16x16x32_bf16(a, b, c, 0, 0, 0);
}

// 4 chained 16x16x16 bf16 MFMAs accumulating into one C/D quad.
__device__ __forceinline__ void mfma16x16_chain4(const bf16x4& a0, const bf16x4& a1,
                                                 const bf16x4& a2, const bf16x4& a3,
                                                 const bf16x4& b0, const bf16x4& b1,
                                                 const bf16x4& b2, const bf16x4& b3,
                                                 f32x4& c) {
  asm volatile(
      "s_nop 2\n\t"
      "v_mfma_f32_16x16x16_bf16 %0, %1, %5, %0\n\t"
      "v_mfma_f32_16x16x16_bf16 %0, %2, %6, %0\n\t"
      "v_mfma_f32_16x16x16_bf16 %0, %3, %7, %0\n\t"
      "v_mfma_f32_16x16x16_bf16 %0, %4, %8, %0"
      : "+v"(c)
      : "v"(a0), "v"(a1), "v"(a2), "v"(a3),
        "v"(b0), "v"(b1), "v"(b2), "v"(b3));
}

// Async global->LDS DMA, 16B per lane. LDS dest is wave-uniform base +
// lane*16 (hardware rule); global src is per-lane.
__device__ __forceinline__ void gload_lds16(const bf16* g, bf16* l) {
  __builtin_amdgcn_global_load_lds(
      (const __attribute__((address_space(1))) unsigned int*)g,
      (__attribute__((address_space(3))) unsigned int*)l, 16, 0, 0);
}

__device__ __forceinline__ void store_c(float* p, float v) { *p = v; }
__device__ __forceinline__ void store_c(bf16* p, float v) { *p = (bf16)v; }

// ---------------------------------------------------------------------------
// fp32 -> bf16 cast, 8 elems/thread
// ---------------------------------------------------------------------------
__global__ __launch_bounds__(256) void cast_bf16(const float* __restrict__ s,
                                                 bf16* __restrict__ d) {
  int i = blockIdx.x * 256 + threadIdx.x;
  float4 a = reinterpret_cast<const float4*>(s)[i * 2];
  float4 b = reinterpret_cast<const float4*>(s)[i * 2 + 1];
  bf16x8 v = {(bf16)a.x, (bf16)a.y, (bf16)a.z, (bf16)a.w,
              (bf16)b.x, (bf16)b.y, (bf16)b.z, (bf16)b.w};
  reinterpret_cast<bf16x8*>(d)[i] = v;
}

// ---------------------------------------------------------------------------
// gemm256: C[M][N] = A[M][K] @ B[N][K]^T, bf16 out. 256x256 tile, BK=32,
// 512 threads (8 waves, 2Mx4N), triple-buffered LDS, prefetch depth 2.
//
// T4 counted-vmcnt pipeline (the m218 lever): per K-step exactly ONE
//   s_waitcnt vmcnt(4)   -- tile t's 4 DMA loads done; tile t+1's 4 loads
//                           REMAIN IN FLIGHT across the barrier
//   s_barrier            -- per-wave count + barrier => all waves' loads done
//   sched_barrier(0)     -- pin: no ds_read/DMA may hoist above (rule #18)
//   stage tile t+2       -- into buf[(t+2)%3]; its last reader was tile t-1,
//                           all waves finished those reads before THIS barrier
//   12x ds_read_b128 + 32 independent MFMAs.
// Wait-math: at the wait of iter t, outstanding = tiles t, t+1 (8 loads);
// vmcnt(4) retires tile t's 4. Final iter: vmcnt(0). Provably race-free.
//
// [256][32] LDS rows are 64B => frag reads are <=2-way bank aliased (free,
// m136) -- no swizzle needed, DMA dest stays linear (rule #21 satisfied
// trivially). LDS 96KB -> 1 block/CU; grid 256 = exactly 1/CU, zero tail.
// T1 XCD swizzle (nwg%8==0, bijective simple form).
// ---------------------------------------------------------------------------
__global__ __launch_bounds__(512, 2) void gemm256(const bf16* __restrict__ A,
                                                  const bf16* __restrict__ B,
                                                  bf16* __restrict__ C,
                                                  int M, int N, int K) {
  __shared__ __align__(16) bf16 As[3][256 * 32];
  __shared__ __align__(16) bf16 Bs[3][256 * 32];

  const int tid  = threadIdx.x;
  const int lane = tid & 63;
  const int wid  = tid >> 6;
  const int quad = lane >> 4, l16 = lane & 15;
  const int wr = wid >> 2, wc = wid & 3;  // 2 M-waves x 4 N-waves

  // XCD-aware swizzle of the 1D grid (nwg multiple of 8)
  const int nbx = N >> 8;
  const int nwg = (M >> 8) * nbx;
  const int cpx = nwg >> 3;
  const int swz = (blockIdx.x & 7) * cpx + (blockIdx.x >> 3);
  const int m0 = (swz / nbx) << 8;
  const int n0 = (swz % nbx) << 8;

  // staging: round it in {0,1}: row = it*128 + tid/4, col = (tid&3)*8
  const int srow = tid >> 2, scol = (tid & 3) * 8;
  const bf16* aSrc0 = &A[(size_t)(m0 + srow) * K + scol];
  const bf16* aSrc1 = &A[(size_t)(m0 + 128 + srow) * K + scol];
  const bf16* bSrc0 = &B[(size_t)(n0 + srow) * K + scol];
  const bf16* bSrc1 = &B[(size_t)(n0 + 128 + srow) * K + scol];

  const f32x4 zero = {0.f, 0.f, 0.f, 0.f};
  f32x4 acc[8][4];
#pragma unroll
  for (int i = 0; i < 8; ++i)
#pragma unroll
    for (int j = 0; j < 4; ++j) acc[i][j] = zero;

  const int NT = K >> 5;

  // prologue: stage tiles 0 and 1
  {
    gload_lds16(aSrc0, &As[0][tid * 8]);
    gload_lds16(aSrc1, &As[0][4096 + tid * 8]);
    gload_lds16(bSrc0, &Bs[0][tid * 8]);
    gload_lds16(bSrc1, &Bs[0][4096 + tid * 8]);
    gload_lds16(aSrc0 + 32, &As[1][tid * 8]);
    gload_lds16(aSrc1 + 32, &As[1][4096 + tid * 8]);
    gload_lds16(bSrc0 + 32, &Bs[1][tid * 8]);
    gload_lds16(bSrc1 + 32, &Bs[1][4096 + tid * 8]);
  }

  int bufC = 0;
  for (int t = 0; t < NT; ++t) {
    if (t == NT - 1) {
      asm volatile("s_waitcnt vmcnt(0)" ::: "memory");
    } else {
      asm volatile("s_waitcnt vmcnt(4)" ::: "memory");
    }
    __builtin_amdgcn_s_barrier();
    __builtin_amdgcn_sched_barrier(0);

    if (t + 2 < NT) {
      int bs = bufC + 2; if (bs >= 3) bs -= 3;
      const int k0 = (t + 2) * 32;
      gload_lds16(aSrc0 + k0, &As[bs][tid * 8]);
      gload_lds16(aSrc1 + k0, &As[bs][4096 + tid * 8]);
      gload_lds16(bSrc0 + k0, &Bs[bs][tid * 8]);
      gload_lds16(bSrc1 + k0, &Bs[bs][4096 + tid * 8]);
    }

    const bf16* AsL = As[bufC];
    const bf16* BsL = Bs[bufC];
    bf16x8 af[8], bfv[4];
#pragma unroll
    for (int fm = 0; fm < 8; ++fm)
      af[fm] = *reinterpret_cast<const bf16x8*>(
          &AsL[(wr * 128 + fm * 16 + l16) * 32 + quad * 8]);
#pragma unroll
    for (int fn = 0; fn < 4; ++fn)
      bfv[fn] = *reinterpret_cast<const bf16x8*>(
          &BsL[(wc * 64 + fn * 16 + l16) * 32 + quad * 8]);
#pragma unroll
    for (int fm = 0; fm < 8; ++fm)
#pragma unroll
      for (int fn = 0; fn < 4; ++fn)
        acc[fm][fn] = mfma16(af[fm], bfv[fn], acc[fm][fn]);

    bufC = bufC + 1 == 3 ? 0 : bufC + 1;
  }

#pragma unroll
  for (int fm = 0; fm < 8; ++fm)
#pragma unroll
    for (int fn = 0; fn < 4; ++fn)
#pragma unroll
      for (int r = 0; r < 4; ++r) {
        int row = m0 + wr * 128 + fm * 16 + quad * 4 + r;
        int col = n0 + wc * 64 + fn * 16 + l16;
        C[(size_t)row * N + col] = (bf16)acc[fm][fn][r];
      }
}

// ---------------------------------------------------------------------------
// gemm_bt v3 (verified): 128x128 tile, 2-phase dbuf, gload_lds staging.
// Kept for gemm2 (N=2048 -> 512 blocks = 2/CU; 256-tile would leave half
// the CUs idle at 128 blocks).
// ---------------------------------------------------------------------------
__device__ __forceinline__ void gemm_step(const bf16* AsL, const bf16* BsL,
                                          int wm, int wn, int l16, int quad,
                                          f32x4 (&acc)[4][4]) {
  bf16x8 af[4], bfr[4];
#pragma unroll
  for (int i = 0; i < 4; ++i)
    af[i] = *reinterpret_cast<const bf16x8*>(&AsL[(wm + i * 16 + l16) * 32 + quad * 8]);
#pragma unroll
  for (int j = 0; j < 4; ++j)
    bfr[j] = *reinterpret_cast<const bf16x8*>(&BsL[(wn + j * 16 + l16) * 32 + quad * 8]);
#pragma unroll
  for (int i = 0; i < 4; ++i)
#pragma unroll
    for (int j = 0; j < 4; ++j)
      acc[i][j] = mfma16(af[i], bfr[j], acc[i][j]);
}

template <typename TC>
__global__ __launch_bounds__(256, 4) void gemm_bt(const bf16* __restrict__ A,
                                                  const bf16* __restrict__ B,
                                                  TC* __restrict__ C,
                                                  int M, int N, int K) {
  __shared__ __align__(16) bf16 As[2][128 * 32];
  __shared__ __align__(16) bf16 Bs[2][128 * 32];

  const int tid  = threadIdx.x;
  const int wave = tid >> 6, lane = tid & 63;
  const int quad = lane >> 4, l16 = lane & 15;
  const int wm = (wave >> 1) * 64, wn = (wave & 1) * 64;
  const int n0 = blockIdx.x * 128, m0 = blockIdx.y * 128;

  const int r0 = tid >> 2;
  const int c0 = (tid & 3) * 8;
  const size_t aBase = (size_t)(m0 + r0) * K + c0;
  const size_t bBase = (size_t)(n0 + r0) * K + c0;
  const size_t rowK64 = (size_t)64 * K;

  const f32x4 zero = {0.f, 0.f, 0.f, 0.f};
  f32x4 acc[4][4];
#pragma unroll
  for (int i = 0; i < 4; ++i)
#pragma unroll
    for (int j = 0; j < 4; ++j) acc[i][j] = zero;

  gload_lds16(&A[aBase],          &As[0][tid * 8]);
  gload_lds16(&A[aBase + rowK64], &As[0][2048 + tid * 8]);
  gload_lds16(&B[bBase],          &Bs[0][tid * 8]);
  gload_lds16(&B[bBase + rowK64], &Bs[0][2048 + tid * 8]);
  __syncthreads();

  int cur = 0;
  for (int k0 = 32; k0 < K; k0 += 32) {
    const int nb = cur ^ 1;
    gload_lds16(&A[aBase + k0],          &As[nb][tid * 8]);
    gload_lds16(&A[aBase + rowK64 + k0], &As[nb][2048 + tid * 8]);
    gload_lds16(&B[bBase + k0],          &Bs[nb][tid * 8]);
    gload_lds16(&B[bBase + rowK64 + k0], &Bs[nb][2048 + tid * 8]);

    gemm_step(As[cur], Bs[cur], wm, wn, l16, quad, acc);

    __syncthreads();
    cur = nb;
  }
  gemm_step(As[cur], Bs[cur], wm, wn, l16, quad, acc);

#pragma unroll
  for (int i = 0; i < 4; ++i)
#pragma unroll
    for (int j = 0; j < 4; ++j)
#pragma unroll
      for (int r = 0; r < 4; ++r) {
        int row = m0 + wm + i * 16 + quad * 4 + r;
        int col = n0 + wn + j * 16 + l16;
        store_c(&C[(size_t)row * N + col], acc[i][j][r]);
      }
}

// ---------------------------------------------------------------------------
// norm_rope v2: one block per token, 256 threads, 4 waves x 6 heads.
// Lane l owns the rope pair (d=l, d=l+64) -> shfl-only RMS reduce (no
// barriers), sincos computed ONCE per thread and reused across 6 heads
// (12x fewer transcendentals), 4096 dispatches instead of 98304.
// ---------------------------------------------------------------------------
__global__ __launch_bounds__(256) void norm_rope(const bf16* __restrict__ qkv,
                                                 const float* __restrict__ qw,
                                                 const float* __restrict__ kw,
                                                 const int* __restrict__ pos,
                                                 bf16* __restrict__ qn,
                                                 bf16* __restrict__ kn) {
  const int t = blockIdx.x;
  const int wv = threadIdx.x >> 6, l = threadIdx.x & 63;

  float inv = exp2f((float)l * (-19.93156856932417f / 64.0f));
  float fr = (float)pos[t] * inv;
  float sn, cs;
  sincosf(fr, &sn, &cs);
  const float qw1 = qw[l], qw2 = qw[l + 64];
  const float kw1 = kw[l], kw2 = kw[l + 64];
  const size_t rowb = (size_t)t * 4096;

#pragma unroll
  for (int i = 0; i < 6; ++i) {
    const int h = wv * 6 + i;            // 0..23, uniform per wave
    const bool isq = h < 16;
    const int col = isq ? h * 128 : 2048 + (h - 16) * 128;
    float x1 = (float)qkv[rowb + col + l];
    float x2 = (float)qkv[rowb + col + l + 64];
    float ss = x1 * x1 + x2 * x2;
#pragma unroll
    for (int o = 32; o >= 1; o >>= 1) ss += __shfl_xor(ss, o);
    float rms = rsqrtf(ss * (1.0f / 128.0f) + 1e-6f);
    float w1 = isq ? qw1 : kw1, w2 = isq ? qw2 : kw2;
    float xn1 = x1 * rms * w1, xn2 = x2 * rms * w2;
    float o1 = xn1 * cs - xn2 * sn;
    float o2 = xn2 * cs + xn1 * sn;
    if (isq) {
      qn[(size_t)t * 2048 + h * 128 + l] = (bf16)o1;
      qn[(size_t)t * 2048 + h * 128 + l + 64] = (bf16)o2;
    } else {
      kn[(size_t)t * 1024 + (h - 16) * 128 + l] = (bf16)o1;
      kn[(size_t)t * 1024 + (h - 16) * 128 + l + 64] = (bf16)o2;
    }
  }
}

// ---------------------------------------------------------------------------
// One-time V transpose — unchanged
// ---------------------------------------------------------------------------
__global__ __launch_bounds__(256) void transpose_v(const bf16* __restrict__ qkv,
                                                   bf16* __restrict__ vt) {
  __shared__ __align__(16) bf16 tile[128 * 72];
  const int t0 = blockIdx.x * 64, kvh = blockIdx.y;
  const int tid = threadIdx.x;
#pragma unroll
  for (int it = 0; it < 2; ++it) {
    int linear = it * 4096 + tid * 16;
    int r = linear >> 7, c = linear & 127;
    union { uint4 v; bf16 e[8]; } u0, u1;
    u0.v = *reinterpret_cast<const uint4*>(
        &qkv[(size_t)(t0 + r) * 4096 + 3072 + kvh * 128 + c]);
    u1.v = *reinterpret_cast<const uint4*>(
        &qkv[(size_t)(t0 + r) * 4096 + 3072 + kvh * 128 + c + 8]);
#pragma unroll
    for (int j = 0; j < 8; ++j) tile[(c + j) * 72 + r] = u0.e[j];
#pragma unroll
    for (int j = 0; j < 8; ++j) tile[(c + 8 + j) * 72 + r] = u1.e[j];
  }
  __syncthreads();
#pragma unroll
  for (int it = 0; it < 4; ++it) {
    int linear = it * 2048 + tid * 8;
    int d = linear >> 6, c = linear & 63;
    uint4 v = *reinterpret_cast<const uint4*>(&tile[d * 72 + c]);
    *reinterpret_cast<uint4*>(&vt[(size_t)(kvh * 128 + d) * 4096 + t0 + c]) = v;
  }
}

// ---------------------------------------------------------------------------
// Flash attention v8 — unchanged from the verified round-3 build.
// ---------------------------------------------------------------------------
__global__ __launch_bounds__(256, 2) void attn(const bf16* __restrict__ q,
                                               const bf16* __restrict__ k,
                                               const bf16* __restrict__ vt,
                                               bf16* __restrict__ out) {
  __shared__ __align__(16) bf16 Ks[2][64 * 128];  // [buf][kv row][dim] swizzled
  __shared__ __align__(16) bf16 Vs[2][128 * 64];  // [buf][dim][kv row] swizzled

  const int head = blockIdx.y, kvh = head >> 1;
  const int bx = blockIdx.x;

  const int tid = threadIdx.x;
  const int wave = tid >> 6, lane = tid & 63;
  const int quad = lane >> 4, l16 = lane & 15;
  const float cExp = 0.08838834764831845f * 1.4426950408889634f; // scale*log2e
  const f32x4 zero = {0.f, 0.f, 0.f, 0.f};

  int kSrc[4], vSrc[4];
#pragma unroll
  for (int it = 0; it < 4; ++it) {
    int r = (wave * 4 + it) * 4 + (lane >> 4);
    kSrc[it] = r * 1024 + kvh * 128 + (((lane & 15) ^ (r & 7)) << 3);
    int d = (wave * 4 + it) * 8 + (lane >> 3);
    vSrc[it] = (kvh * 128 + d) * 4096 + (((lane & 7) ^ (lane >> 3)) << 3);
  }

  const int kswz = (l16 & 7) << 3;
  int koff[4], voff[4];
#pragma unroll
  for (int s = 0; s < 4; ++s) {
    koff[s] = (s * 32 + quad * 8) ^ kswz;
    voff[s] = (s * 16 + quad * 4) ^ kswz;
  }

#pragma unroll
  for (int it = 0; it < 4; ++it) {
    gload_lds16(&k[kSrc[it]], &Ks[0][(wave * 4 + it) * 512]);
    gload_lds16(&vt[vSrc[it]], &Vs[0][(wave * 4 + it) * 512]);
  }
  int cur = 0;

#pragma unroll
  for (int phase = 0; phase < 2; ++phase) {
    const int qt = phase == 0 ? bx : 63 - bx;
    const int q0 = qt * 64;
    const int kend = q0 + 64;
    const int qrow = q0 + wave * 16 + l16;

    bf16x8 qf[4];
#pragma unroll
    for (int s = 0; s < 4; ++s)
      qf[s] = *reinterpret_cast<const bf16x8*>(
          &q[(size_t)qrow * 2048 + head * 128 + s * 32 + quad * 8]);

    f32x4 o_acc[8];
#pragma unroll
    for (int dt = 0; dt < 8; ++dt) o_acc[dt] = zero;
    float m_i = -3.0e38f, l_i = 0.f;

    for (int k0 = 0; k0 < kend; k0 += 64) {
      __syncthreads();

      int nk0 = -1;
      if (k0 + 64 < kend)     nk0 = k0 + 64;
      else if (phase == 0)    nk0 = 0;
      if (nk0 >= 0) {
#pragma unroll
        for (int it = 0; it < 4; ++it) {
          gload_lds16(&k[kSrc[it] + nk0 * 1024],
                      &Ks[cur ^ 1][(wave * 4 + it) * 512]);
          gload_lds16(&vt[vSrc[it] + nk0],
                      &Vs[cur ^ 1][(wave * 4 + it) * 512]);
        }
      }

      const bf16* KsL = Ks[cur];
      const bf16* VsL = Vs[cur];

      f32x4 s_acc[4];
      __builtin_amdgcn_s_setprio(1);
#pragma unroll
      for (int mt = 0; mt < 4; ++mt) {
        bf16x8 kf[4];
#pragma unroll
        for (int ks = 0; ks < 4; ++ks)
          kf[ks] = *reinterpret_cast<const bf16x8*>(
              &KsL[(mt * 16 + l16) * 128 + koff[ks]]);
        f32x4 sa = zero;
#pragma unroll
        for (int ks = 0; ks < 4; ++ks) sa = mfma16(kf[ks], qf[ks], sa);
        s_acc[mt] = sa;
      }
      __builtin_amdgcn_s_setprio(0);

      if (k0 == q0) {
        int tq = wave * 16 + l16;
#pragma unroll
        for (int mt = 0; mt < 4; ++mt)
#pragma unroll
          for (int r = 0; r < 4; ++r) {
            int tk = mt * 16 + quad * 4 + r;
            if (tk > tq) s_acc[mt][r] = -3.0e38f;
          }
      }

      {
        float mx = -3.0e38f;
#pragma unroll
        for (int mt = 0; mt < 4; ++mt)
#pragma unroll
          for (int r = 0; r < 4; ++r) mx = fmaxf(mx, s_acc[mt][r]);
        mx = fmaxf(mx, __shfl_xor(mx, 16));
        mx = fmaxf(mx, __shfl_xor(mx, 32));
        if (!__all((mx - m_i) * cExp <= 8.0f)) {
          float mn = fmaxf(m_i, mx);
          float al = exp2f((m_i - mn) * cExp);
          m_i = mn;
          l_i *= al;
#pragma unroll
          for (int dt = 0; dt < 8; ++dt)
#pragma unroll
            for (int r = 0; r < 4; ++r) o_acc[dt][r] *= al;
        }
        float nmc = -m_i * cExp;
        float rs = 0.f;
#pragma unroll
        for (int mt = 0; mt < 4; ++mt)
#pragma unroll
          for (int r = 0; r < 4; ++r) {
            float pe = exp2f(fmaf(s_acc[mt][r], cExp, nmc));
            s_acc[mt][r] = pe;
            rs += pe;
          }
        rs += __shfl_xor(rs, 16);
        rs += __shfl_xor(rs, 32);
        l_i += rs;
      }

      bf16x4 pb[4];
#pragma unroll
      for (int mt = 0; mt < 4; ++mt) {
        bf16x4 t;
#pragma unroll
        for (int r = 0; r < 4; ++r) t[r] = (bf16)s_acc[mt][r];
        pb[mt] = t;
      }

      __builtin_amdgcn_s_setprio(1);
#pragma unroll
      for (int dt = 0; dt < 8; ++dt) {
        const bf16* vrow = &VsL[(dt * 16 + l16) * 64];
        bf16x4 va0 = *reinterpret_cast<const bf16x4*>(&vrow[voff[0]]);
        bf16x4 va1 = *reinterpret_cast<const bf16x4*>(&vrow[voff[1]]);
        bf16x4 va2 = *reinterpret_cast<const bf16x4*>(&vrow[voff[2]]);
        bf16x4 va3 = *reinterpret_cast<const bf16x4*>(&vrow[voff[3]]);
        mfma16x16_chain4(va0, va1, va2, va3, pb[0], pb[1], pb[2], pb[3],
                         o_acc[dt]);
      }
      __builtin_amdgcn_s_setprio(0);
      cur ^= 1;
    }

    float rl = __builtin_amdgcn_rcpf(l_i);
#pragma unroll
    for (int dt = 0; dt < 8; ++dt) {
      bf16x4 ov;
#pragma unroll
      for (int r = 0; r < 4; ++r) ov[r] = (bf16)(o_acc[dt][r] * rl);
      *reinterpret_cast<bf16x4*>(
          &out[(size_t)qrow * 2048 + head * 128 + dt * 16 + quad * 4]) = ov;
    }
  }
}

// ---------------------------------------------------------------------------
extern "C" void kernel_launch(void* const* d_in, const int* in_sizes, int n_in,
                              void* d_out, int out_size, void* d_ws, size_t ws_size,
                              hipStream_t stream) {
  const float* hidden = (const float*)d_in[0];
  const float* qkv_w  = (const float*)d_in[1];
  const float* qnw    = (const float*)d_in[2];
  const float* knw    = (const float*)d_in[3];
  const float* o_w    = (const float*)d_in[4];
  const int*   pos    = (const int*)d_in[5];

  bf16* qkv = (bf16*)d_ws;                       // 4096*4096
  bf16* qn  = qkv + (size_t)4096 * 4096;         // 4096*2048
  bf16* kn  = qn  + (size_t)4096 * 2048;         // 4096*1024
  bf16* vt  = kn  + (size_t)4096 * 1024;         // 1024*4096
  bf16* ao  = vt  + (size_t)1024 * 4096;         // 4096*2048
  bf16* hb  = ao;   // bf16 hidden, dead before attn writes ao
  bf16* wq  = kn;   // bf16 qkv_w, dead before norm_rope/transpose write kn/vt
  bf16* wo  = qn;   // bf16 o_w, cast after attn (qn dead)
  float* out = (float*)d_out;

  cast_bf16<<<4096, 256, 0, stream>>>(hidden, hb);
  cast_bf16<<<4096, 256, 0, stream>>>(qkv_w, wq);
  gemm256<<<256, 512, 0, stream>>>(hb, wq, qkv, 4096, 4096, 2048);
  norm_rope<<<4096, 256, 0, stream>>>(qkv, qnw, knw, pos, qn, kn);
  transpose_v<<<dim3(64, 8), 256, 0, stream>>>(qkv, vt);
  attn<<<dim3(32, 16), 256, 0, stream>>>(qn, kn, vt, ao);
  cast_bf16<<<2048, 256, 0, stream>>>(o_w, wo);
  gemm_bt<<<dim3(16, 32), 256, 0, stream>>>(ao, wo, out, 4096, 2048, 2048);
}